// Round 1
// baseline (2146.568 us; speedup 1.0000x reference)
//
#include <hip/hip_runtime.h>
#include <math.h>

#define BDIM 4
#define NDIM 8
#define TDIM 512
#define DDIM 512
#define HEADS 8
#define HDIM 64
#define NGRP 4
#define DG 128
#define NTROWS (NDIM * TDIM)        // 4096
#define MROWS (BDIM * NTROWS)       // 16384
#define EPSGN 1e-3f

// ---------------- GroupNorm statistics (2-stage deterministic reduction) ----------------
// grid: (16 groups = b*4+g, 32 chunks); 256 threads
__global__ __launch_bounds__(256) void gn_stats_partial(const float* __restrict__ x,
                                                        float* __restrict__ part) {
  const int grp = blockIdx.x;
  const int chunk = blockIdx.y;
  const int b = grp >> 2, g = grp & 3;
  const float* base = x + (size_t)b * NTROWS * DDIM + g * DG;
  const int r0 = chunk * (NTROWS / 32);  // 128 rows per chunk
  float s = 0.f, sq = 0.f;
  for (int i = threadIdx.x; i < 128 * 32; i += 256) {
    const int r = i >> 5, c4 = (i & 31) << 2;
    const float4 v = *(const float4*)(base + (size_t)(r0 + r) * DDIM + c4);
    s += v.x + v.y + v.z + v.w;
    sq += v.x * v.x + v.y * v.y + v.z * v.z + v.w * v.w;
  }
#pragma unroll
  for (int o = 32; o > 0; o >>= 1) { s += __shfl_down(s, o); sq += __shfl_down(sq, o); }
  __shared__ float red[8];
  const int wid = threadIdx.x >> 6;
  if ((threadIdx.x & 63) == 0) { red[wid * 2] = s; red[wid * 2 + 1] = sq; }
  __syncthreads();
  if (threadIdx.x == 0) {
    float S = 0.f, SQ = 0.f;
    for (int w = 0; w < 4; ++w) { S += red[w * 2]; SQ += red[w * 2 + 1]; }
    part[(grp * 32 + chunk) * 2] = S;
    part[(grp * 32 + chunk) * 2 + 1] = SQ;
  }
}

__global__ void gn_finalize(const float* __restrict__ part, float* __restrict__ stat) {
  const int g = threadIdx.x;
  if (g < 16) {
    float S = 0.f, SQ = 0.f;
    for (int c = 0; c < 32; ++c) { S += part[(g * 32 + c) * 2]; SQ += part[(g * 32 + c) * 2 + 1]; }
    const float inv = 1.f / (float)(NTROWS * DG);
    const float mu = S * inv;
    const float var = SQ * inv - mu * mu;
    stat[g * 2] = mu;
    stat[g * 2 + 1] = rsqrtf(var + EPSGN);
  }
}

// ---------------- Generic fp32 NT GEMM: C[M,512] = A'[M,512] @ W^T ----------------
// A' = optional fused GroupNorm on A (stats uniform per tile: batch = bm>>12, group = k0>>7).
// EPI: 0 = C=acc ; 1 = C=leakyrelu(acc+bias) ; 2 = C=acc+bias+init ; 3 = C+=acc+bias
// BM=BN=128, BK=16, 256 threads, 8x8 per thread.
template <int GN_A, int EPI>
__global__ __launch_bounds__(256, 2) void gemm_nt(const float* __restrict__ A,
                                                  const float* __restrict__ W,
                                                  float* __restrict__ C,
                                                  const float* __restrict__ astat,
                                                  const float* __restrict__ bias,
                                                  const float* __restrict__ init) {
  __shared__ __align__(16) float As[16][132];
  __shared__ __align__(16) float Ws[16][132];
  const int tid = threadIdx.x;
  const int bm = blockIdx.x << 7;
  const int bn = blockIdx.y << 7;
  const int batch = bm >> 12;
  const int tm0 = (tid >> 4) << 3;
  const int tn0 = (tid & 15) << 3;
  const int lrow = tid >> 2;
  const int lk = (tid & 3) << 2;
  float acc[8][8];
#pragma unroll
  for (int i = 0; i < 8; ++i)
#pragma unroll
    for (int j = 0; j < 8; ++j) acc[i][j] = 0.f;

  const float* Ap0 = A + (size_t)(bm + lrow) * DDIM + lk;
  const float* Ap1 = Ap0 + (size_t)64 * DDIM;
  const float* Wp0 = W + (size_t)(bn + lrow) * DDIM + lk;
  const float* Wp1 = Wp0 + (size_t)64 * DDIM;

  for (int k0 = 0; k0 < DDIM; k0 += 16) {
    float4 a0 = *(const float4*)(Ap0 + k0);
    float4 a1 = *(const float4*)(Ap1 + k0);
    float4 w0 = *(const float4*)(Wp0 + k0);
    float4 w1 = *(const float4*)(Wp1 + k0);
    if (GN_A) {
      const float* st = astat + (((batch << 2) | (k0 >> 7)) << 1);
      const float mu = st[0], rs = st[1];
      a0.x = (a0.x - mu) * rs; a0.y = (a0.y - mu) * rs;
      a0.z = (a0.z - mu) * rs; a0.w = (a0.w - mu) * rs;
      a1.x = (a1.x - mu) * rs; a1.y = (a1.y - mu) * rs;
      a1.z = (a1.z - mu) * rs; a1.w = (a1.w - mu) * rs;
    }
    __syncthreads();
    As[lk + 0][lrow] = a0.x; As[lk + 1][lrow] = a0.y;
    As[lk + 2][lrow] = a0.z; As[lk + 3][lrow] = a0.w;
    As[lk + 0][64 + lrow] = a1.x; As[lk + 1][64 + lrow] = a1.y;
    As[lk + 2][64 + lrow] = a1.z; As[lk + 3][64 + lrow] = a1.w;
    Ws[lk + 0][lrow] = w0.x; Ws[lk + 1][lrow] = w0.y;
    Ws[lk + 2][lrow] = w0.z; Ws[lk + 3][lrow] = w0.w;
    Ws[lk + 0][64 + lrow] = w1.x; Ws[lk + 1][64 + lrow] = w1.y;
    Ws[lk + 2][64 + lrow] = w1.z; Ws[lk + 3][64 + lrow] = w1.w;
    __syncthreads();
#pragma unroll
    for (int kk = 0; kk < 16; ++kk) {
      float av[8], wv[8];
      *(float4*)(av) = *(const float4*)&As[kk][tm0];
      *(float4*)(av + 4) = *(const float4*)&As[kk][tm0 + 4];
      *(float4*)(wv) = *(const float4*)&Ws[kk][tn0];
      *(float4*)(wv + 4) = *(const float4*)&Ws[kk][tn0 + 4];
#pragma unroll
      for (int i = 0; i < 8; ++i)
#pragma unroll
        for (int j = 0; j < 8; ++j) acc[i][j] += av[i] * wv[j];
    }
  }

#pragma unroll
  for (int i = 0; i < 8; ++i) {
    const int row = bm + tm0 + i;
    float* cp = C + (size_t)row * DDIM + bn + tn0;
    float vals[8];
#pragma unroll
    for (int j = 0; j < 8; ++j) {
      float v = acc[i][j];
      if (EPI == 1 || EPI == 2 || EPI == 3) v += bias[bn + tn0 + j];
      if (EPI == 1) v = v > 0.f ? v : 0.01f * v;
      vals[j] = v;
    }
    if (EPI == 2) {
      const float* ip = init + (size_t)row * DDIM + bn + tn0;
#pragma unroll
      for (int j = 0; j < 8; ++j) vals[j] += ip[j];
    }
    if (EPI == 3) {
#pragma unroll
      for (int j = 0; j < 8; ++j) vals[j] += cp[j];
    }
    *(float4*)cp = make_float4(vals[0], vals[1], vals[2], vals[3]);
    *(float4*)(cp + 4) = make_float4(vals[4], vals[5], vals[6], vals[7]);
  }
}

// ---------------- Attention: one block per (b,n,h) ----------------
// GN on q_pre/k_pre fused (per-head group = h>>1 is constant per block).
// 16-query tiles; logits+softmax in LDS; attn weights streamed to d_out; PV streamed.
__global__ __launch_bounds__(256) void attn_kernel(const float* __restrict__ qp,
                                                   const float* __restrict__ kp,
                                                   const float* __restrict__ vv,
                                                   const float* __restrict__ qstat,
                                                   const float* __restrict__ kstat,
                                                   float* __restrict__ ao,
                                                   float* __restrict__ aw) {
  const int bid = blockIdx.x;  // ((b*8+n)*8+h)
  const int h = bid & 7;
  const int b = bid >> 6;
  const int g = h >> 1;
  const int tid = threadIdx.x;
  const int sidx = ((b << 2) | g) << 1;
  const float qmu = qstat[sidx], qrs = qstat[sidx + 1];
  const float kmu = kstat[sidx], krs = kstat[sidx + 1];
  const size_t sb = (size_t)(bid >> 3) * (TDIM * DDIM);
  const float* Q = qp + sb + h * HDIM;
  const float* Kp = kp + sb + h * HDIM;
  const float* Vp = vv + sb + h * HDIM;
  float* AO = ao + sb + h * HDIM;
  float* AW = aw + (size_t)bid * (TDIM * TDIM);

  __shared__ __align__(16) float qs[16][68];
  __shared__ __align__(16) float ks[64][68];  // K^T tile during logits; V tile during PV
  __shared__ __align__(16) float lt[16][512];

  const int qi = tid >> 4;             // 0..15
  const int x4 = (tid & 15) << 2;      // 0..60

  for (int q0 = 0; q0 < TDIM; q0 += 16) {
    {  // load Q tile 16x64, fused GN
      float4 qv = *(const float4*)(Q + (size_t)(q0 + qi) * DDIM + x4);
      qv.x = (qv.x - qmu) * qrs; qv.y = (qv.y - qmu) * qrs;
      qv.z = (qv.z - qmu) * qrs; qv.w = (qv.w - qmu) * qrs;
      *(float4*)&qs[qi][x4] = qv;
    }
    // ---- logits ----
    for (int k0 = 0; k0 < TDIM; k0 += 64) {
      __syncthreads();
      {  // load K tile transposed (64 keys x 64 ch), fused GN
        const int r = tid >> 2;
        const int cbase = (tid & 3) << 4;
#pragma unroll
        for (int cc = 0; cc < 16; cc += 4) {
          float4 kv = *(const float4*)(Kp + (size_t)(k0 + r) * DDIM + cbase + cc);
          kv.x = (kv.x - kmu) * krs; kv.y = (kv.y - kmu) * krs;
          kv.z = (kv.z - kmu) * krs; kv.w = (kv.w - kmu) * krs;
          ks[cbase + cc + 0][r] = kv.x;
          ks[cbase + cc + 1][r] = kv.y;
          ks[cbase + cc + 2][r] = kv.z;
          ks[cbase + cc + 3][r] = kv.w;
        }
      }
      __syncthreads();
      float acc0 = 0.f, acc1 = 0.f, acc2 = 0.f, acc3 = 0.f;
#pragma unroll 16
      for (int c = 0; c < 64; ++c) {
        const float qv = qs[qi][c];
        const float4 kv = *(const float4*)&ks[c][x4];
        acc0 += qv * kv.x; acc1 += qv * kv.y;
        acc2 += qv * kv.z; acc3 += qv * kv.w;
      }
      lt[qi][k0 + x4 + 0] = acc0 * 0.125f;
      lt[qi][k0 + x4 + 1] = acc1 * 0.125f;
      lt[qi][k0 + x4 + 2] = acc2 * 0.125f;
      lt[qi][k0 + x4 + 3] = acc3 * 0.125f;
    }
    __syncthreads();
    // ---- softmax (4 waves x 4 rows each), write weights to d_out ----
    {
      const int wv = tid >> 6, ln = tid & 63;
      for (int r = wv; r < 16; r += 4) {
        float4 x0 = *(const float4*)&lt[r][ln * 8];
        float4 x1 = *(const float4*)&lt[r][ln * 8 + 4];
        float mx = fmaxf(fmaxf(fmaxf(x0.x, x0.y), fmaxf(x0.z, x0.w)),
                         fmaxf(fmaxf(x1.x, x1.y), fmaxf(x1.z, x1.w)));
#pragma unroll
        for (int o = 1; o < 64; o <<= 1) mx = fmaxf(mx, __shfl_xor(mx, o));
        float e0 = expf(x0.x - mx), e1 = expf(x0.y - mx);
        float e2 = expf(x0.z - mx), e3 = expf(x0.w - mx);
        float e4 = expf(x1.x - mx), e5 = expf(x1.y - mx);
        float e6 = expf(x1.z - mx), e7 = expf(x1.w - mx);
        float sm = e0 + e1 + e2 + e3 + e4 + e5 + e6 + e7;
#pragma unroll
        for (int o = 1; o < 64; o <<= 1) sm += __shfl_xor(sm, o);
        const float inv = 1.f / sm;
        float4 p0 = make_float4(e0 * inv, e1 * inv, e2 * inv, e3 * inv);
        float4 p1 = make_float4(e4 * inv, e5 * inv, e6 * inv, e7 * inv);
        *(float4*)&lt[r][ln * 8] = p0;
        *(float4*)&lt[r][ln * 8 + 4] = p1;
        float* awp = AW + (size_t)(q0 + r) * TDIM + ln * 8;
        *(float4*)awp = p0;
        *(float4*)(awp + 4) = p1;
      }
    }
    __syncthreads();
    // ---- PV: out(16x64) += P(16x512) @ V(512x64) ----
    float o0 = 0.f, o1 = 0.f, o2 = 0.f, o3 = 0.f;
    for (int k0 = 0; k0 < TDIM; k0 += 64) {
      __syncthreads();
      {  // load V tile (64 keys x 64 ch), natural layout
        const int r = tid >> 2;
        const int cbase = (tid & 3) << 4;
#pragma unroll
        for (int cc = 0; cc < 16; cc += 4) {
          *(float4*)&ks[r][cbase + cc] =
              *(const float4*)(Vp + (size_t)(k0 + r) * DDIM + cbase + cc);
        }
      }
      __syncthreads();
#pragma unroll 16
      for (int kj = 0; kj < 64; ++kj) {
        const float p = lt[qi][k0 + kj];
        const float4 v4 = *(const float4*)&ks[kj][x4];
        o0 += p * v4.x; o1 += p * v4.y;
        o2 += p * v4.z; o3 += p * v4.w;
      }
    }
    float* aop = AO + (size_t)(q0 + qi) * DDIM + x4;
    *(float4*)aop = make_float4(o0, o1, o2, o3);
    __syncthreads();  // protect lt/qs/ks before next q-tile overwrites
  }
}

// ---------------- launcher ----------------
extern "C" void kernel_launch(void* const* d_in, const int* in_sizes, int n_in,
                              void* d_out, int out_size, void* d_ws, size_t ws_size,
                              hipStream_t stream) {
  const float* in_f = (const float*)d_in[1];
  const float* in_fkv = (const float*)d_in[2];
  const float* Wq = (const float*)d_in[3];
  const float* Wk = (const float*)d_in[4];
  const float* Wv = (const float*)d_in[5];
  const float* Wz = (const float*)d_in[6];
  const float* bz = (const float*)d_in[7];
  const float* W1 = (const float*)d_in[8];
  const float* b1 = (const float*)d_in[9];
  const float* W2 = (const float*)d_in[10];
  const float* b2 = (const float*)d_in[11];

  float* out_f = (float*)d_out;
  float* attw = out_f + (size_t)MROWS * DDIM;

  float* ws = (float*)d_ws;
  const size_t TS = (size_t)MROWS * DDIM;  // 8388608 floats per intermediate tensor
  float* q_pre = ws;
  float* k_pre = ws + TS;
  float* vbuf = ws + 2 * TS;
  float* h1 = ws + 3 * TS;
  float* aout = ws + 4 * TS;
  float* part = ws + 5 * TS;
  float* stat_f = part + 1024;
  float* stat_kv = stat_f + 32;
  float* stat_q = stat_kv + 32;
  float* stat_k = stat_q + 32;

  dim3 sg(16, 32);
  gn_stats_partial<<<sg, 256, 0, stream>>>(in_f, part);
  gn_finalize<<<1, 64, 0, stream>>>(part, stat_f);
  gn_stats_partial<<<sg, 256, 0, stream>>>(in_fkv, part);
  gn_finalize<<<1, 64, 0, stream>>>(part, stat_kv);

  dim3 gg(MROWS / 128, DDIM / 128);
  gemm_nt<1, 0><<<gg, 256, 0, stream>>>(in_f, Wq, q_pre, stat_f, nullptr, nullptr);
  gemm_nt<1, 0><<<gg, 256, 0, stream>>>(in_fkv, Wk, k_pre, stat_kv, nullptr, nullptr);
  gemm_nt<1, 0><<<gg, 256, 0, stream>>>(in_fkv, Wv, vbuf, stat_kv, nullptr, nullptr);
  gemm_nt<1, 1><<<gg, 256, 0, stream>>>(in_f, W1, h1, stat_f, b1, nullptr);

  gn_stats_partial<<<sg, 256, 0, stream>>>(q_pre, part);
  gn_finalize<<<1, 64, 0, stream>>>(part, stat_q);
  gn_stats_partial<<<sg, 256, 0, stream>>>(k_pre, part);
  gn_finalize<<<1, 64, 0, stream>>>(part, stat_k);

  attn_kernel<<<BDIM * NDIM * HEADS, 256, 0, stream>>>(q_pre, k_pre, vbuf, stat_q, stat_k,
                                                       aout, attw);

  gemm_nt<0, 2><<<gg, 256, 0, stream>>>(aout, Wz, out_f, nullptr, bz, in_f);
  gemm_nt<0, 3><<<gg, 256, 0, stream>>>(h1, W2, out_f, nullptr, b2, nullptr);
}

// Round 2
// 333.616 us; speedup vs baseline: 6.4342x; 6.4342x over previous
//
#include <hip/hip_runtime.h>
#include <math.h>

#define TDIM 512
#define DDIM 512
#define NTROWS 4096
#define MROWS 16384
#define EPSGN 1e-3f

typedef __attribute__((ext_vector_type(8))) short bf16x8;
typedef __attribute__((ext_vector_type(4))) float f32x4;
typedef __attribute__((ext_vector_type(8))) unsigned short us8;
typedef __attribute__((ext_vector_type(4))) unsigned short us4;

__device__ __forceinline__ unsigned short f2b(float f) {
  unsigned int u = __float_as_uint(f);
  return (unsigned short)((u + 0x7fffu + ((u >> 16) & 1u)) >> 16);
}
__device__ __forceinline__ float b2f(unsigned short h) {
  return __uint_as_float(((unsigned int)h) << 16);
}

#define GLOAD16(g, l)                                                                   \
  __builtin_amdgcn_global_load_lds((const __attribute__((address_space(1))) void*)(g),  \
                                   (__attribute__((address_space(3))) void*)(l), 16, 0, 0)

// ---------------- GroupNorm statistics (fp32 input) ----------------
__global__ __launch_bounds__(256) void gn_stats_partial(const float* __restrict__ x,
                                                        float* __restrict__ part) {
  const int grp = blockIdx.x;
  const int chunk = blockIdx.y;
  const int b = grp >> 2, g = grp & 3;
  const float* base = x + (size_t)b * NTROWS * DDIM + g * 128;
  const int r0 = chunk * (NTROWS / 32);
  float s = 0.f, sq = 0.f;
  for (int i = threadIdx.x; i < 128 * 32; i += 256) {
    const int r = i >> 5, c4 = (i & 31) << 2;
    const float4 v = *(const float4*)(base + (size_t)(r0 + r) * DDIM + c4);
    s += v.x + v.y + v.z + v.w;
    sq += v.x * v.x + v.y * v.y + v.z * v.z + v.w * v.w;
  }
#pragma unroll
  for (int o = 32; o > 0; o >>= 1) { s += __shfl_down(s, o); sq += __shfl_down(sq, o); }
  __shared__ float red[8];
  const int wid = threadIdx.x >> 6;
  if ((threadIdx.x & 63) == 0) { red[wid * 2] = s; red[wid * 2 + 1] = sq; }
  __syncthreads();
  if (threadIdx.x == 0) {
    float S = 0.f, SQ = 0.f;
    for (int w = 0; w < 4; ++w) { S += red[w * 2]; SQ += red[w * 2 + 1]; }
    part[(grp * 32 + chunk) * 2] = S;
    part[(grp * 32 + chunk) * 2 + 1] = SQ;
  }
}

// ---------------- GroupNorm statistics (bf16 input) ----------------
__global__ __launch_bounds__(256) void gn_stats_partial_b16(const unsigned short* __restrict__ x,
                                                            float* __restrict__ part) {
  const int grp = blockIdx.x;
  const int chunk = blockIdx.y;
  const int b = grp >> 2, g = grp & 3;
  const unsigned short* base = x + (size_t)b * NTROWS * DDIM + g * 128;
  const int r0 = chunk * (NTROWS / 32);
  float s = 0.f, sq = 0.f;
  for (int i = threadIdx.x; i < 128 * 16; i += 256) {
    const int r = i >> 4, c8 = (i & 15) << 3;
    const us8 v = *(const us8*)(base + (size_t)(r0 + r) * DDIM + c8);
#pragma unroll
    for (int j = 0; j < 8; ++j) { const float f = b2f(v[j]); s += f; sq += f * f; }
  }
#pragma unroll
  for (int o = 32; o > 0; o >>= 1) { s += __shfl_down(s, o); sq += __shfl_down(sq, o); }
  __shared__ float red[8];
  const int wid = threadIdx.x >> 6;
  if ((threadIdx.x & 63) == 0) { red[wid * 2] = s; red[wid * 2 + 1] = sq; }
  __syncthreads();
  if (threadIdx.x == 0) {
    float S = 0.f, SQ = 0.f;
    for (int w = 0; w < 4; ++w) { S += red[w * 2]; SQ += red[w * 2 + 1]; }
    part[(grp * 32 + chunk) * 2] = S;
    part[(grp * 32 + chunk) * 2 + 1] = SQ;
  }
}

__global__ void gn_finalize(const float* __restrict__ part, float* __restrict__ stat) {
  const int g = threadIdx.x;
  if (g < 16) {
    float S = 0.f, SQ = 0.f;
    for (int c = 0; c < 32; ++c) { S += part[(g * 32 + c) * 2]; SQ += part[(g * 32 + c) * 2 + 1]; }
    const float inv = 1.f / (float)(NTROWS * 128);
    const float mu = S * inv;
    const float var = SQ * inv - mu * mu;
    stat[g * 2] = mu;
    stat[g * 2 + 1] = rsqrtf(var + EPSGN);
  }
}

// ---------------- fp32 -> bf16 with fused GroupNorm ----------------
__global__ __launch_bounds__(256) void cvt_gn(const float* __restrict__ x,
                                              const float* __restrict__ stat,
                                              unsigned short* __restrict__ o) {
  const int NC = MROWS * DDIM / 8;
  for (int c = blockIdx.x * 256 + threadIdx.x; c < NC; c += gridDim.x * 256) {
    const int e = c * 8;
    const int row = e >> 9;
    const int ch = e & 511;
    const int sidx = (((row >> 12) << 2) | (ch >> 7)) << 1;
    const float mu = stat[sidx], rs = stat[sidx + 1];
    const float4 f0 = *(const float4*)(x + e);
    const float4 f1 = *(const float4*)(x + e + 4);
    us8 v;
    v[0] = f2b((f0.x - mu) * rs); v[1] = f2b((f0.y - mu) * rs);
    v[2] = f2b((f0.z - mu) * rs); v[3] = f2b((f0.w - mu) * rs);
    v[4] = f2b((f1.x - mu) * rs); v[5] = f2b((f1.y - mu) * rs);
    v[6] = f2b((f1.z - mu) * rs); v[7] = f2b((f1.w - mu) * rs);
    *(us8*)(o + e) = v;
  }
}

// ---------------- weight fp32 -> bf16 (6 tensors) ----------------
__global__ __launch_bounds__(256) void cvt_w(const float* w0, const float* w1, const float* w2,
                                             const float* w3, const float* w4, const float* w5,
                                             unsigned short* __restrict__ dst) {
  const float* s;
  switch (blockIdx.y) {
    case 0: s = w0; break; case 1: s = w1; break; case 2: s = w2; break;
    case 3: s = w3; break; case 4: s = w4; break; default: s = w5; break;
  }
  unsigned short* d = dst + (size_t)blockIdx.y * 262144;
  const int c = blockIdx.x * 256 + threadIdx.x;
  const float4 f0 = *(const float4*)(s + (size_t)c * 8);
  const float4 f1 = *(const float4*)(s + (size_t)c * 8 + 4);
  us8 o;
  o[0] = f2b(f0.x); o[1] = f2b(f0.y); o[2] = f2b(f0.z); o[3] = f2b(f0.w);
  o[4] = f2b(f1.x); o[5] = f2b(f1.y); o[6] = f2b(f1.z); o[7] = f2b(f1.w);
  *(us8*)(d + (size_t)c * 8) = o;
}

// ---------------- bf16 MFMA GEMM: C[M,512] = A[M,512] @ B[512,512]^T ----------------
// EPI: 0 = bf16 C ; 1 = bf16 leakyrelu(acc+bias) ; 2 = bf16 transposed (vT) ;
//      3 = fp32 acc+bias+init ; 4 = fp32 C += acc+bias
template <int EPI>
__global__ __launch_bounds__(256) void gemm_bf16(const unsigned short* __restrict__ A,
                                                 const unsigned short* __restrict__ B,
                                                 unsigned short* __restrict__ Cb,
                                                 float* __restrict__ Cf,
                                                 const float* __restrict__ bias,
                                                 const float* __restrict__ init) {
  __shared__ __align__(16) unsigned short As[128 * 64];
  __shared__ __align__(16) unsigned short Bs[128 * 64];
  const int tid = threadIdx.x;
  const int wave = tid >> 6, lane = tid & 63;
  const int bm = blockIdx.x << 7, bn = blockIdx.y << 7;
  const int wr = (wave >> 1) << 6;
  const int wc = (wave & 1) << 6;
  const int lr = lane & 15, lg = lane >> 4;

  f32x4 acc[4][4] = {};

  const int srow = lane >> 3;                // 0..7 within chunk
  const int sslot = (lane & 7) ^ srow;       // pre-swizzled source slot

  for (int k0 = 0; k0 < 512; k0 += 64) {
    __syncthreads();
#pragma unroll
    for (int i = 0; i < 4; ++i) {
      const int ci = wave * 4 + i;
      const int row = ci * 8 + srow;
      const unsigned short* ga = A + (size_t)(bm + row) * 512 + k0 + sslot * 8;
      const unsigned short* gb = B + (size_t)(bn + row) * 512 + k0 + sslot * 8;
      GLOAD16(ga, (char*)As + ci * 1024);
      GLOAD16(gb, (char*)Bs + ci * 1024);
    }
    __syncthreads();
#pragma unroll
    for (int kk = 0; kk < 64; kk += 32) {
      bf16x8 af[4], bfr[4];
#pragma unroll
      for (int i = 0; i < 4; ++i) {
        const int row = wr + i * 16 + lr;
        af[i] = *(const bf16x8*)&As[row * 64 + ((((kk >> 3) + lg) ^ (row & 7)) << 3)];
      }
#pragma unroll
      for (int j = 0; j < 4; ++j) {
        const int row = wc + j * 16 + lr;
        bfr[j] = *(const bf16x8*)&Bs[row * 64 + ((((kk >> 3) + lg) ^ (row & 7)) << 3)];
      }
#pragma unroll
      for (int i = 0; i < 4; ++i)
#pragma unroll
        for (int j = 0; j < 4; ++j)
          acc[i][j] = __builtin_amdgcn_mfma_f32_16x16x32_bf16(af[i], bfr[j], acc[i][j], 0, 0, 0);
    }
  }

#pragma unroll
  for (int i = 0; i < 4; ++i) {
    const int row0 = bm + wr + i * 16 + lg * 4;
#pragma unroll
    for (int j = 0; j < 4; ++j) {
      const int col = bn + wc + j * 16 + lr;
      if (EPI == 0) {
#pragma unroll
        for (int r = 0; r < 4; ++r)
          Cb[(size_t)(row0 + r) * 512 + col] = f2b(acc[i][j][r]);
      } else if (EPI == 1) {
        const float bb = bias[col];
#pragma unroll
        for (int r = 0; r < 4; ++r) {
          float v = acc[i][j][r] + bb;
          v = v > 0.f ? v : 0.01f * v;
          Cb[(size_t)(row0 + r) * 512 + col] = f2b(v);
        }
      } else if (EPI == 2) {
        us4 pk;
#pragma unroll
        for (int r = 0; r < 4; ++r) pk[r] = f2b(acc[i][j][r]);
        *(us4*)&Cb[((size_t)(row0 >> 9) * 512 + col) * 512 + (row0 & 511)] = pk;
      } else if (EPI == 3) {
        const float bb = bias[col];
#pragma unroll
        for (int r = 0; r < 4; ++r) {
          const size_t o = (size_t)(row0 + r) * 512 + col;
          Cf[o] = acc[i][j][r] + bb + init[o];
        }
      } else {
        const float bb = bias[col];
#pragma unroll
        for (int r = 0; r < 4; ++r) {
          const size_t o = (size_t)(row0 + r) * 512 + col;
          Cf[o] += acc[i][j][r] + bb;
        }
      }
    }
  }
}

// ---------------- attention logits + softmax -> P (fp32 to d_out) ----------------
// grid (256 heads, 16 q-tiles of 32), 256 threads / 4 waves.
__global__ __launch_bounds__(256) void attn_logits(const unsigned short* __restrict__ q16,
                                                   const unsigned short* __restrict__ k16,
                                                   const float* __restrict__ qstat,
                                                   const float* __restrict__ kstat,
                                                   float* __restrict__ aw) {
  __shared__ __align__(16) unsigned short Ks[256 * 64];
  __shared__ __align__(16) unsigned short Qs[32 * 64];
  __shared__ float WM[4][32];
  __shared__ float WS[4][32];
  const int bid = blockIdx.x;
  const int q0 = blockIdx.y << 5;
  const int h = bid & 7;
  const int b = bid >> 6;
  const int tid = threadIdx.x;
  const int w = tid >> 6, lane = tid & 63;
  const int lr = lane & 15, lg = lane >> 4;
  const int sidx = ((b << 2) | (h >> 1)) << 1;
  const float qmu = qstat[sidx], qrs = qstat[sidx + 1];
  const float kmu = kstat[sidx], krs = kstat[sidx + 1];
  const unsigned short* Qg = q16 + (size_t)(bid >> 3) * (512 * 512) + h * 64;
  const unsigned short* Kg = k16 + (size_t)(bid >> 3) * (512 * 512) + h * 64;

  {  // stage Q 32x64 (GN fused, swizzled)
    const int row = tid >> 3, slot = tid & 7;
    const us8 v = *(const us8*)(Qg + (size_t)(q0 + row) * 512 + slot * 8);
    us8 o;
#pragma unroll
    for (int j = 0; j < 8; ++j) o[j] = f2b((b2f(v[j]) - qmu) * qrs);
    *(us8*)&Qs[row * 64 + ((slot ^ (row & 7)) << 3)] = o;
  }

  f32x4 sc[2][8] = {};

  for (int half = 0; half < 2; ++half) {
    __syncthreads();
    for (int it = 0; it < 8; ++it) {  // stage K 256x64
      const int row = it * 32 + (tid >> 3), slot = tid & 7;
      const us8 v = *(const us8*)(Kg + (size_t)(half * 256 + row) * 512 + slot * 8);
      us8 o;
#pragma unroll
      for (int j = 0; j < 8; ++j) o[j] = f2b((b2f(v[j]) - kmu) * krs);
      *(us8*)&Ks[row * 64 + ((slot ^ (row & 7)) << 3)] = o;
    }
    __syncthreads();
#pragma unroll
    for (int kk = 0; kk < 64; kk += 32) {
      bf16x8 aq[2];
#pragma unroll
      for (int qf = 0; qf < 2; ++qf) {
        const int row = qf * 16 + lr;
        aq[qf] = *(const bf16x8*)&Qs[row * 64 + ((((kk >> 3) + lg) ^ (row & 7)) << 3)];
      }
#pragma unroll
      for (int kf = 0; kf < 4; ++kf) {
        const int row = w * 64 + kf * 16 + lr;
        const bf16x8 bk = *(const bf16x8*)&Ks[row * 64 + ((((kk >> 3) + lg) ^ (row & 7)) << 3)];
#pragma unroll
        for (int qf = 0; qf < 2; ++qf)
          sc[qf][half * 4 + kf] =
              __builtin_amdgcn_mfma_f32_16x16x32_bf16(aq[qf], bk, sc[qf][half * 4 + kf], 0, 0, 0);
      }
    }
  }

  // ---- softmax: row max/sum (16-lane shfl) + cross-wave LDS reduce ----
  float Mv[2][4], inv[2][4];
#pragma unroll
  for (int qf = 0; qf < 2; ++qf)
#pragma unroll
    for (int r = 0; r < 4; ++r) {
      float m = sc[qf][0][r];
#pragma unroll
      for (int kf = 1; kf < 8; ++kf) m = fmaxf(m, sc[qf][kf][r]);
#pragma unroll
      for (int o = 1; o < 16; o <<= 1) m = fmaxf(m, __shfl_xor(m, o));
      Mv[qf][r] = m;
    }
  if (lr == 0) {
#pragma unroll
    for (int qf = 0; qf < 2; ++qf)
#pragma unroll
      for (int r = 0; r < 4; ++r) WM[w][qf * 16 + lg * 4 + r] = Mv[qf][r];
  }
  __syncthreads();
#pragma unroll
  for (int qf = 0; qf < 2; ++qf)
#pragma unroll
    for (int r = 0; r < 4; ++r) {
      const int q = qf * 16 + lg * 4 + r;
      Mv[qf][r] = fmaxf(fmaxf(WM[0][q], WM[1][q]), fmaxf(WM[2][q], WM[3][q]));
    }
  float sl[2][4] = {};
#pragma unroll
  for (int qf = 0; qf < 2; ++qf)
#pragma unroll
    for (int kf = 0; kf < 8; ++kf) {
      f32x4 v = sc[qf][kf];
#pragma unroll
      for (int r = 0; r < 4; ++r) {
        const float e = __expf((v[r] - Mv[qf][r]) * 0.125f);
        v[r] = e;
        sl[qf][r] += e;
      }
      sc[qf][kf] = v;
    }
#pragma unroll
  for (int qf = 0; qf < 2; ++qf)
#pragma unroll
    for (int r = 0; r < 4; ++r) {
      float s = sl[qf][r];
#pragma unroll
      for (int o = 1; o < 16; o <<= 1) s += __shfl_xor(s, o);
      sl[qf][r] = s;
    }
  if (lr == 0) {
#pragma unroll
    for (int qf = 0; qf < 2; ++qf)
#pragma unroll
      for (int r = 0; r < 4; ++r) WS[w][qf * 16 + lg * 4 + r] = sl[qf][r];
  }
  __syncthreads();
#pragma unroll
  for (int qf = 0; qf < 2; ++qf)
#pragma unroll
    for (int r = 0; r < 4; ++r) {
      const int q = qf * 16 + lg * 4 + r;
      inv[qf][r] = 1.f / (WS[0][q] + WS[1][q] + WS[2][q] + WS[3][q]);
    }

  float* AWp = aw + ((size_t)bid * 512 + q0) * 512;
#pragma unroll
  for (int qf = 0; qf < 2; ++qf)
#pragma unroll
    for (int kf = 0; kf < 8; ++kf) {
      const int k = ((kf >> 2) * 256) + w * 64 + (kf & 3) * 16 + lr;
#pragma unroll
      for (int r = 0; r < 4; ++r) {
        const int q = qf * 16 + lg * 4 + r;
        AWp[(size_t)q * 512 + k] = sc[qf][kf][r] * inv[qf][r];
      }
    }
}

// ---------------- attention PV: out(64q x 64d) = P @ V, per (head, q-tile) ----------------
__global__ __launch_bounds__(256) void attn_pv(const float* __restrict__ aw,
                                               const unsigned short* __restrict__ vT,
                                               unsigned short* __restrict__ ao16) {
  __shared__ __align__(16) unsigned short Ps[64 * 64];
  __shared__ __align__(16) unsigned short Vs[64 * 64];
  const int bid = blockIdx.x, qm = blockIdx.y;
  const int h = bid & 7;
  const int tid = threadIdx.x;
  const int w = tid >> 6, lane = tid & 63;
  const int lr = lane & 15, lg = lane >> 4;
  const int qh = (w >> 1) * 32, dh = (w & 1) * 32;
  const float* Pg = aw + ((size_t)bid * 512 + qm * 64) * 512;
  const unsigned short* Vg = vT + ((size_t)(bid >> 3) * 512 + h * 64) * 512;

  f32x4 acc[2][2] = {};
  const int srow = tid >> 2;
  const int scb = (tid & 3) << 4;

  for (int ks = 0; ks < 512; ks += 64) {
    __syncthreads();
    {
      const float* ps = Pg + (size_t)srow * 512 + ks + scb;
      const float4 f0 = *(const float4*)ps, f1 = *(const float4*)(ps + 4);
      const float4 g0 = *(const float4*)(ps + 8), g1 = *(const float4*)(ps + 12);
      us8 p0, p1;
      p0[0] = f2b(f0.x); p0[1] = f2b(f0.y); p0[2] = f2b(f0.z); p0[3] = f2b(f0.w);
      p0[4] = f2b(f1.x); p0[5] = f2b(f1.y); p0[6] = f2b(f1.z); p0[7] = f2b(f1.w);
      p1[0] = f2b(g0.x); p1[1] = f2b(g0.y); p1[2] = f2b(g0.z); p1[3] = f2b(g0.w);
      p1[4] = f2b(g1.x); p1[5] = f2b(g1.y); p1[6] = f2b(g1.z); p1[7] = f2b(g1.w);
      const int s0 = (scb >> 3) ^ (srow & 7), s1 = ((scb >> 3) + 1) ^ (srow & 7);
      *(us8*)&Ps[srow * 64 + (s0 << 3)] = p0;
      *(us8*)&Ps[srow * 64 + (s1 << 3)] = p1;
      const unsigned short* vs = Vg + (size_t)srow * 512 + ks + scb;
      const us8 v0 = *(const us8*)vs, v1 = *(const us8*)(vs + 8);
      *(us8*)&Vs[srow * 64 + (s0 << 3)] = v0;
      *(us8*)&Vs[srow * 64 + (s1 << 3)] = v1;
    }
    __syncthreads();
#pragma unroll
    for (int kk = 0; kk < 64; kk += 32) {
      bf16x8 pa[2], vb[2];
#pragma unroll
      for (int qf = 0; qf < 2; ++qf) {
        const int row = qh + qf * 16 + lr;
        pa[qf] = *(const bf16x8*)&Ps[row * 64 + ((((kk >> 3) + lg) ^ (row & 7)) << 3)];
      }
#pragma unroll
      for (int df = 0; df < 2; ++df) {
        const int row = dh + df * 16 + lr;
        vb[df] = *(const bf16x8*)&Vs[row * 64 + ((((kk >> 3) + lg) ^ (row & 7)) << 3)];
      }
#pragma unroll
      for (int qf = 0; qf < 2; ++qf)
#pragma unroll
        for (int df = 0; df < 2; ++df)
          acc[qf][df] = __builtin_amdgcn_mfma_f32_16x16x32_bf16(pa[qf], vb[df], acc[qf][df], 0, 0, 0);
    }
  }

  const int growb = (bid >> 3) * 512 + qm * 64 + qh;
#pragma unroll
  for (int qf = 0; qf < 2; ++qf)
#pragma unroll
    for (int df = 0; df < 2; ++df)
#pragma unroll
      for (int r = 0; r < 4; ++r) {
        const int grow = growb + qf * 16 + lg * 4 + r;
        const int col = h * 64 + dh + df * 16 + lr;
        ao16[(size_t)grow * 512 + col] = f2b(acc[qf][df][r]);
      }
}

// ---------------- launcher ----------------
extern "C" void kernel_launch(void* const* d_in, const int* in_sizes, int n_in,
                              void* d_out, int out_size, void* d_ws, size_t ws_size,
                              hipStream_t stream) {
  const float* in_f = (const float*)d_in[1];
  const float* in_fkv = (const float*)d_in[2];
  const float* Wq = (const float*)d_in[3];
  const float* Wk = (const float*)d_in[4];
  const float* Wv = (const float*)d_in[5];
  const float* Wz = (const float*)d_in[6];
  const float* bz = (const float*)d_in[7];
  const float* W1 = (const float*)d_in[8];
  const float* b1 = (const float*)d_in[9];
  const float* W2 = (const float*)d_in[10];
  const float* b2 = (const float*)d_in[11];

  float* out_f = (float*)d_out;
  float* attw = out_f + (size_t)MROWS * DDIM;

  const size_t TSB = (size_t)MROWS * DDIM;
  unsigned short* us = (unsigned short*)d_ws;
  unsigned short* a16 = us;
  unsigned short* akv16 = us + TSB;
  unsigned short* q16 = us + 2 * TSB;
  unsigned short* k16 = us + 3 * TSB;
  unsigned short* h16 = us + 4 * TSB;
  unsigned short* ao16 = us + 5 * TSB;
  unsigned short* vT = us + 6 * TSB;
  unsigned short* w16 = us + 7 * TSB;  // 6 * 262144 ushorts
  float* fbase = (float*)(us + 7 * TSB + 6 * 262144);
  float* part = fbase;
  float* stat_f = fbase + 1024;
  float* stat_kv = fbase + 1056;
  float* stat_q = fbase + 1088;
  float* stat_k = fbase + 1120;

  dim3 sg(16, 32);
  gn_stats_partial<<<sg, 256, 0, stream>>>(in_f, part);
  gn_finalize<<<1, 64, 0, stream>>>(part, stat_f);
  gn_stats_partial<<<sg, 256, 0, stream>>>(in_fkv, part);
  gn_finalize<<<1, 64, 0, stream>>>(part, stat_kv);

  cvt_gn<<<2048, 256, 0, stream>>>(in_f, stat_f, a16);
  cvt_gn<<<2048, 256, 0, stream>>>(in_fkv, stat_kv, akv16);
  cvt_w<<<dim3(128, 6), 256, 0, stream>>>(Wq, Wk, Wv, Wz, W1, W2, w16);

  dim3 gg(128, 4);
  gemm_bf16<0><<<gg, 256, 0, stream>>>(a16, w16 + 0 * 262144, q16, nullptr, nullptr, nullptr);
  gemm_bf16<0><<<gg, 256, 0, stream>>>(akv16, w16 + 1 * 262144, k16, nullptr, nullptr, nullptr);
  gemm_bf16<2><<<gg, 256, 0, stream>>>(akv16, w16 + 2 * 262144, vT, nullptr, nullptr, nullptr);
  gemm_bf16<1><<<gg, 256, 0, stream>>>(a16, w16 + 4 * 262144, h16, nullptr, b1, nullptr);

  gn_stats_partial_b16<<<sg, 256, 0, stream>>>(q16, part);
  gn_finalize<<<1, 64, 0, stream>>>(part, stat_q);
  gn_stats_partial_b16<<<sg, 256, 0, stream>>>(k16, part);
  gn_finalize<<<1, 64, 0, stream>>>(part, stat_k);

  attn_logits<<<dim3(256, 16), 256, 0, stream>>>(q16, k16, stat_q, stat_k, attw);
  attn_pv<<<dim3(256, 8), 256, 0, stream>>>(attw, vT, ao16);

  gemm_bf16<3><<<gg, 256, 0, stream>>>(ao16, w16 + 3 * 262144, nullptr, out_f, bz, in_f);
  gemm_bf16<4><<<gg, 256, 0, stream>>>(h16, w16 + 5 * 262144, nullptr, out_f, b2, nullptr);
}

// Round 3
// 287.053 us; speedup vs baseline: 7.4779x; 1.1622x over previous
//
#include <hip/hip_runtime.h>
#include <math.h>

#define TDIM 512
#define DDIM 512
#define NTROWS 4096
#define MROWS 16384
#define EPSGN 1e-3f

typedef __attribute__((ext_vector_type(8))) short bf16x8;
typedef __attribute__((ext_vector_type(4))) float f32x4;
typedef __attribute__((ext_vector_type(8))) unsigned short us8;
typedef __attribute__((ext_vector_type(4))) unsigned short us4;

__device__ __forceinline__ unsigned short f2b(float f) {
  unsigned int u = __float_as_uint(f);
  return (unsigned short)((u + 0x7fffu + ((u >> 16) & 1u)) >> 16);
}
__device__ __forceinline__ float b2f(unsigned short h) {
  return __uint_as_float(((unsigned int)h) << 16);
}

#define GLOAD16(g, l)                                                                   \
  __builtin_amdgcn_global_load_lds((const __attribute__((address_space(1))) void*)(g),  \
                                   (__attribute__((address_space(3))) void*)(l), 16, 0, 0)

// ---------------- GroupNorm statistics (fp32 input) ----------------
__global__ __launch_bounds__(256) void gn_stats_partial(const float* __restrict__ x,
                                                        float* __restrict__ part) {
  const int grp = blockIdx.x;
  const int chunk = blockIdx.y;
  const int b = grp >> 2, g = grp & 3;
  const float* base = x + (size_t)b * NTROWS * DDIM + g * 128;
  const int r0 = chunk * (NTROWS / 32);
  float s = 0.f, sq = 0.f;
  for (int i = threadIdx.x; i < 128 * 32; i += 256) {
    const int r = i >> 5, c4 = (i & 31) << 2;
    const float4 v = *(const float4*)(base + (size_t)(r0 + r) * DDIM + c4);
    s += v.x + v.y + v.z + v.w;
    sq += v.x * v.x + v.y * v.y + v.z * v.z + v.w * v.w;
  }
#pragma unroll
  for (int o = 32; o > 0; o >>= 1) { s += __shfl_down(s, o); sq += __shfl_down(sq, o); }
  __shared__ float red[8];
  const int wid = threadIdx.x >> 6;
  if ((threadIdx.x & 63) == 0) { red[wid * 2] = s; red[wid * 2 + 1] = sq; }
  __syncthreads();
  if (threadIdx.x == 0) {
    float S = 0.f, SQ = 0.f;
    for (int w = 0; w < 4; ++w) { S += red[w * 2]; SQ += red[w * 2 + 1]; }
    part[(grp * 32 + chunk) * 2] = S;
    part[(grp * 32 + chunk) * 2 + 1] = SQ;
  }
}

// ---------------- fp32 -> bf16 with fused GroupNorm (inline finalize) ----------------
__global__ __launch_bounds__(256) void cvt_gn(const float* __restrict__ x,
                                              const float* __restrict__ part,
                                              unsigned short* __restrict__ o) {
  __shared__ float sstat[32];
  if (threadIdx.x < 16) {
    const float* p = part + threadIdx.x * 64;
    float S = 0.f, SQ = 0.f;
    for (int c = 0; c < 32; ++c) { S += p[c * 2]; SQ += p[c * 2 + 1]; }
    const float inv = 1.f / (float)(NTROWS * 128);
    const float mu = S * inv;
    const float var = SQ * inv - mu * mu;
    sstat[threadIdx.x * 2] = mu;
    sstat[threadIdx.x * 2 + 1] = rsqrtf(var + EPSGN);
  }
  __syncthreads();
  const int NC = MROWS * DDIM / 8;
  for (int c = blockIdx.x * 256 + threadIdx.x; c < NC; c += gridDim.x * 256) {
    const int e = c * 8;
    const int row = e >> 9;
    const int ch = e & 511;
    const int sidx = (((row >> 12) << 2) | (ch >> 7)) << 1;
    const float mu = sstat[sidx], rs = sstat[sidx + 1];
    const float4 f0 = *(const float4*)(x + (size_t)e);
    const float4 f1 = *(const float4*)(x + (size_t)e + 4);
    us8 v;
    v[0] = f2b((f0.x - mu) * rs); v[1] = f2b((f0.y - mu) * rs);
    v[2] = f2b((f0.z - mu) * rs); v[3] = f2b((f0.w - mu) * rs);
    v[4] = f2b((f1.x - mu) * rs); v[5] = f2b((f1.y - mu) * rs);
    v[6] = f2b((f1.z - mu) * rs); v[7] = f2b((f1.w - mu) * rs);
    *(us8*)(o + (size_t)e) = v;
  }
}

// ---------------- weight fp32 -> bf16 (6 tensors) ----------------
__global__ __launch_bounds__(256) void cvt_w(const float* w0, const float* w1, const float* w2,
                                             const float* w3, const float* w4, const float* w5,
                                             unsigned short* __restrict__ dst) {
  const float* s;
  switch (blockIdx.y) {
    case 0: s = w0; break; case 1: s = w1; break; case 2: s = w2; break;
    case 3: s = w3; break; case 4: s = w4; break; default: s = w5; break;
  }
  unsigned short* d = dst + (size_t)blockIdx.y * 262144;
  const int c = blockIdx.x * 256 + threadIdx.x;
  const float4 f0 = *(const float4*)(s + (size_t)c * 8);
  const float4 f1 = *(const float4*)(s + (size_t)c * 8 + 4);
  us8 o;
  o[0] = f2b(f0.x); o[1] = f2b(f0.y); o[2] = f2b(f0.z); o[3] = f2b(f0.w);
  o[4] = f2b(f1.x); o[5] = f2b(f1.y); o[6] = f2b(f1.z); o[7] = f2b(f1.w);
  *(us8*)(d + (size_t)c * 8) = o;
}

// ---------------- bf16 MFMA GEMM: C[M,512] = A[M,512] @ B[512,512]^T ----------------
// EPI: 0 = bf16 C ; 1 = bf16 leakyrelu(acc+bias) ; 2 = bf16 transposed (vT)
// STATS: write per-block GroupNorm partials (sum, sumsq) from fp32 accumulators.
template <int EPI, int STATS>
__global__ __launch_bounds__(256) void gemm_bf16(const unsigned short* __restrict__ A,
                                                 const unsigned short* __restrict__ B,
                                                 unsigned short* __restrict__ Cb,
                                                 const float* __restrict__ bias,
                                                 float* __restrict__ part) {
  __shared__ __align__(16) unsigned short As[128 * 64];
  __shared__ __align__(16) unsigned short Bs[128 * 64];
  const int tid = threadIdx.x;
  const int wave = tid >> 6, lane = tid & 63;
  const int bm = blockIdx.x << 7, bn = blockIdx.y << 7;
  const int wr = (wave >> 1) << 6;
  const int wc = (wave & 1) << 6;
  const int lr = lane & 15, lg = lane >> 4;

  f32x4 acc[4][4] = {};

  const int srow = lane >> 3;
  const int sslot = (lane & 7) ^ srow;

  for (int k0 = 0; k0 < 512; k0 += 64) {
    __syncthreads();
#pragma unroll
    for (int i = 0; i < 4; ++i) {
      const int ci = wave * 4 + i;
      const int row = ci * 8 + srow;
      GLOAD16(A + (size_t)(bm + row) * 512 + k0 + sslot * 8, (char*)As + ci * 1024);
      GLOAD16(B + (size_t)(bn + row) * 512 + k0 + sslot * 8, (char*)Bs + ci * 1024);
    }
    __syncthreads();
#pragma unroll
    for (int kk = 0; kk < 64; kk += 32) {
      bf16x8 af[4], bfr[4];
#pragma unroll
      for (int i = 0; i < 4; ++i) {
        const int row = wr + i * 16 + lr;
        af[i] = *(const bf16x8*)&As[row * 64 + ((((kk >> 3) + lg) ^ (row & 7)) << 3)];
      }
#pragma unroll
      for (int j = 0; j < 4; ++j) {
        const int row = wc + j * 16 + lr;
        bfr[j] = *(const bf16x8*)&Bs[row * 64 + ((((kk >> 3) + lg) ^ (row & 7)) << 3)];
      }
#pragma unroll
      for (int i = 0; i < 4; ++i)
#pragma unroll
        for (int j = 0; j < 4; ++j)
          acc[i][j] = __builtin_amdgcn_mfma_f32_16x16x32_bf16(af[i], bfr[j], acc[i][j], 0, 0, 0);
    }
  }

#pragma unroll
  for (int i = 0; i < 4; ++i) {
    const int row0 = bm + wr + i * 16 + lg * 4;
#pragma unroll
    for (int j = 0; j < 4; ++j) {
      const int col = bn + wc + j * 16 + lr;
      if (EPI == 0) {
#pragma unroll
        for (int r = 0; r < 4; ++r)
          Cb[(size_t)(row0 + r) * 512 + col] = f2b(acc[i][j][r]);
      } else if (EPI == 1) {
        const float bb = bias[col];
#pragma unroll
        for (int r = 0; r < 4; ++r) {
          float v = acc[i][j][r] + bb;
          v = v > 0.f ? v : 0.01f * v;
          Cb[(size_t)(row0 + r) * 512 + col] = f2b(v);
        }
      } else {
        us4 pk;
#pragma unroll
        for (int r = 0; r < 4; ++r) pk[r] = f2b(acc[i][j][r]);
        *(us4*)&Cb[((size_t)(row0 >> 9) * 512 + col) * 512 + (row0 & 511)] = pk;
      }
    }
  }

  if (STATS) {
    float s = 0.f, sq = 0.f;
#pragma unroll
    for (int i = 0; i < 4; ++i)
#pragma unroll
      for (int j = 0; j < 4; ++j)
#pragma unroll
        for (int r = 0; r < 4; ++r) { const float v = acc[i][j][r]; s += v; sq += v * v; }
#pragma unroll
    for (int o = 32; o > 0; o >>= 1) { s += __shfl_xor(s, o); sq += __shfl_xor(sq, o); }
    __shared__ float red[8];
    if (lane == 0) { red[wave * 2] = s; red[wave * 2 + 1] = sq; }
    __syncthreads();
    if (tid == 0) {
      const float S = red[0] + red[2] + red[4] + red[6];
      const float SQ = red[1] + red[3] + red[5] + red[7];
      const int batch = blockIdx.x >> 5, slot = blockIdx.x & 31, g = blockIdx.y;
      const int idx = ((((batch << 2) | g) << 5) | slot) << 1;
      part[idx] = S;
      part[idx + 1] = SQ;
    }
  }
}

// ---------------- final GEMM: out = [ao|h1](K=1024) @ [Wz|W2]^T + bz+b2 + in_f ----------------
__global__ __launch_bounds__(256) void gemm_final(const unsigned short* __restrict__ A0,
                                                  const unsigned short* __restrict__ A1,
                                                  const unsigned short* __restrict__ B0,
                                                  const unsigned short* __restrict__ B1,
                                                  float* __restrict__ Cf,
                                                  const float* __restrict__ bias0,
                                                  const float* __restrict__ bias1,
                                                  const float* __restrict__ init) {
  __shared__ __align__(16) unsigned short As[128 * 64];
  __shared__ __align__(16) unsigned short Bs[128 * 64];
  const int tid = threadIdx.x;
  const int wave = tid >> 6, lane = tid & 63;
  const int bm = blockIdx.x << 7, bn = blockIdx.y << 7;
  const int wr = (wave >> 1) << 6;
  const int wc = (wave & 1) << 6;
  const int lr = lane & 15, lg = lane >> 4;

  f32x4 acc[4][4] = {};
  const int srow = lane >> 3;
  const int sslot = (lane & 7) ^ srow;

  for (int k0 = 0; k0 < 1024; k0 += 64) {
    const unsigned short* Ab = (k0 < 512) ? A0 : A1;
    const unsigned short* Bb = (k0 < 512) ? B0 : B1;
    const int kl = k0 & 511;
    __syncthreads();
#pragma unroll
    for (int i = 0; i < 4; ++i) {
      const int ci = wave * 4 + i;
      const int row = ci * 8 + srow;
      GLOAD16(Ab + (size_t)(bm + row) * 512 + kl + sslot * 8, (char*)As + ci * 1024);
      GLOAD16(Bb + (size_t)(bn + row) * 512 + kl + sslot * 8, (char*)Bs + ci * 1024);
    }
    __syncthreads();
#pragma unroll
    for (int kk = 0; kk < 64; kk += 32) {
      bf16x8 af[4], bfr[4];
#pragma unroll
      for (int i = 0; i < 4; ++i) {
        const int row = wr + i * 16 + lr;
        af[i] = *(const bf16x8*)&As[row * 64 + ((((kk >> 3) + lg) ^ (row & 7)) << 3)];
      }
#pragma unroll
      for (int j = 0; j < 4; ++j) {
        const int row = wc + j * 16 + lr;
        bfr[j] = *(const bf16x8*)&Bs[row * 64 + ((((kk >> 3) + lg) ^ (row & 7)) << 3)];
      }
#pragma unroll
      for (int i = 0; i < 4; ++i)
#pragma unroll
        for (int j = 0; j < 4; ++j)
          acc[i][j] = __builtin_amdgcn_mfma_f32_16x16x32_bf16(af[i], bfr[j], acc[i][j], 0, 0, 0);
    }
  }

#pragma unroll
  for (int i = 0; i < 4; ++i) {
    const int row0 = bm + wr + i * 16 + lg * 4;
#pragma unroll
    for (int j = 0; j < 4; ++j) {
      const int col = bn + wc + j * 16 + lr;
      const float bb = bias0[col] + bias1[col];
#pragma unroll
      for (int r = 0; r < 4; ++r) {
        const size_t o = (size_t)(row0 + r) * 512 + col;
        Cf[o] = acc[i][j][r] + bb + init[o];
      }
    }
  }
}

// ---------------- fused attention: QK^T + softmax + P-write + PV ----------------
// grid (256 heads, 8 q-tiles of 64), 256 threads / 4 waves.
__global__ __launch_bounds__(256) void attn_fused(const unsigned short* __restrict__ q16,
                                                  const unsigned short* __restrict__ k16,
                                                  const unsigned short* __restrict__ vT,
                                                  const float* __restrict__ part_q,
                                                  const float* __restrict__ part_k,
                                                  float* __restrict__ aw,
                                                  unsigned short* __restrict__ ao16) {
  __shared__ __align__(16) unsigned short Qs[64 * 64];
  __shared__ __align__(16) unsigned short Ks[256 * 64];  // K tiles; then V [64][256]
  __shared__ __align__(16) unsigned short Ps[64 * 256];
  __shared__ float WM[4][64];
  __shared__ float WS[4][64];
  __shared__ float sstat[4];

  const int bid = blockIdx.x;
  const int q0 = blockIdx.y << 6;
  const int h = bid & 7;
  const int b = bid >> 6;
  const int tid = threadIdx.x;
  const int w = tid >> 6, lane = tid & 63;
  const int lr = lane & 15, lg = lane >> 4;

  if (tid < 2) {
    const float* p = (tid == 0 ? part_q : part_k) + ((((b << 2) | (h >> 1)) << 5) << 1);
    float S = 0.f, SQ = 0.f;
    for (int c = 0; c < 32; ++c) { S += p[c * 2]; SQ += p[c * 2 + 1]; }
    const float inv = 1.f / (float)(NTROWS * 128);
    const float mu = S * inv;
    const float var = SQ * inv - mu * mu;
    sstat[tid * 2] = mu;
    sstat[tid * 2 + 1] = rsqrtf(var + EPSGN);
  }
  __syncthreads();
  const float qmu = sstat[0], qrs = sstat[1], kmu = sstat[2], krs = sstat[3];

  const size_t hb = (size_t)(bid >> 3) * (512 * 512);
  const unsigned short* Qg = q16 + hb + h * 64;
  const unsigned short* Kg = k16 + hb + h * 64;
  const unsigned short* Vg = vT + hb + (size_t)h * 64 * 512;

  {  // stage Q 64x64, GN fused, swizzled
    const int row = tid >> 2, cb = (tid & 3) << 4;
    const us8 v0 = *(const us8*)(Qg + (size_t)(q0 + row) * 512 + cb);
    const us8 v1 = *(const us8*)(Qg + (size_t)(q0 + row) * 512 + cb + 8);
    us8 o0, o1;
#pragma unroll
    for (int j = 0; j < 8; ++j) {
      o0[j] = f2b((b2f(v0[j]) - qmu) * qrs);
      o1[j] = f2b((b2f(v1[j]) - qmu) * qrs);
    }
    const int s0 = (cb >> 3) ^ (row & 7);
    const int s1 = ((cb >> 3) + 1) ^ (row & 7);
    *(us8*)&Qs[row * 64 + (s0 << 3)] = o0;
    *(us8*)&Qs[row * 64 + (s1 << 3)] = o1;
  }

  f32x4 sc[4][8] = {};

#pragma unroll
  for (int half = 0; half < 2; ++half) {
    __syncthreads();
#pragma unroll
    for (int it = 0; it < 8; ++it) {  // stage K half (256x64), GN fused
      const int row = it * 32 + (tid >> 3), slot = tid & 7;
      const us8 v = *(const us8*)(Kg + (size_t)(half * 256 + row) * 512 + (slot << 3));
      us8 o;
#pragma unroll
      for (int j = 0; j < 8; ++j) o[j] = f2b((b2f(v[j]) - kmu) * krs);
      *(us8*)&Ks[row * 64 + ((slot ^ (row & 7)) << 3)] = o;
    }
    __syncthreads();
#pragma unroll
    for (int kk = 0; kk < 64; kk += 32) {
      bf16x8 aq[4];
#pragma unroll
      for (int qf = 0; qf < 4; ++qf) {
        const int row = qf * 16 + lr;
        aq[qf] = *(const bf16x8*)&Qs[row * 64 + ((((kk >> 3) + lg) ^ (row & 7)) << 3)];
      }
#pragma unroll
      for (int kf = 0; kf < 4; ++kf) {
        const int row = w * 64 + kf * 16 + lr;
        const bf16x8 bk = *(const bf16x8*)&Ks[row * 64 + ((((kk >> 3) + lg) ^ (row & 7)) << 3)];
#pragma unroll
        for (int qf = 0; qf < 4; ++qf)
          sc[qf][half * 4 + kf] =
              __builtin_amdgcn_mfma_f32_16x16x32_bf16(aq[qf], bk, sc[qf][half * 4 + kf], 0, 0, 0);
      }
    }
  }

  // ---- softmax ----
  float Mv[4][4];
#pragma unroll
  for (int qf = 0; qf < 4; ++qf)
#pragma unroll
    for (int r = 0; r < 4; ++r) {
      float m = sc[qf][0][r];
#pragma unroll
      for (int kf = 1; kf < 8; ++kf) m = fmaxf(m, sc[qf][kf][r]);
#pragma unroll
      for (int o = 1; o < 16; o <<= 1) m = fmaxf(m, __shfl_xor(m, o));
      Mv[qf][r] = m;
    }
  if (lr == 0) {
#pragma unroll
    for (int qf = 0; qf < 4; ++qf)
#pragma unroll
      for (int r = 0; r < 4; ++r) WM[w][qf * 16 + lg * 4 + r] = Mv[qf][r];
  }
  __syncthreads();
#pragma unroll
  for (int qf = 0; qf < 4; ++qf)
#pragma unroll
    for (int r = 0; r < 4; ++r) {
      const int q = qf * 16 + lg * 4 + r;
      Mv[qf][r] = fmaxf(fmaxf(WM[0][q], WM[1][q]), fmaxf(WM[2][q], WM[3][q]));
    }
  float sl[4][4] = {};
#pragma unroll
  for (int qf = 0; qf < 4; ++qf)
#pragma unroll
    for (int kf = 0; kf < 8; ++kf) {
      f32x4 v = sc[qf][kf];
#pragma unroll
      for (int r = 0; r < 4; ++r) {
        const float e = __expf((v[r] - Mv[qf][r]) * 0.125f);
        v[r] = e;
        sl[qf][r] += e;
      }
      sc[qf][kf] = v;
    }
#pragma unroll
  for (int qf = 0; qf < 4; ++qf)
#pragma unroll
    for (int r = 0; r < 4; ++r) {
      float s = sl[qf][r];
#pragma unroll
      for (int o = 1; o < 16; o <<= 1) s += __shfl_xor(s, o);
      sl[qf][r] = s;
    }
  if (lr == 0) {
#pragma unroll
    for (int qf = 0; qf < 4; ++qf)
#pragma unroll
      for (int r = 0; r < 4; ++r) WS[w][qf * 16 + lg * 4 + r] = sl[qf][r];
  }
  __syncthreads();
#pragma unroll
  for (int qf = 0; qf < 4; ++qf)
#pragma unroll
    for (int r = 0; r < 4; ++r) {
      const int q = qf * 16 + lg * 4 + r;
      const float inv = 1.f / (WS[0][q] + WS[1][q] + WS[2][q] + WS[3][q]);
#pragma unroll
      for (int kf = 0; kf < 8; ++kf) sc[qf][kf][r] *= inv;  // normalize in-place
    }

  // ---- write P (fp32) to d_out ----
  float* AWp = aw + ((size_t)bid * 512 + q0) * 512;
#pragma unroll
  for (int qf = 0; qf < 4; ++qf)
#pragma unroll
    for (int kfi = 0; kfi < 8; ++kfi) {
      const int k = ((kfi >> 2) << 8) + w * 64 + ((kfi & 3) << 4) + lr;
#pragma unroll
      for (int r = 0; r < 4; ++r)
        AWp[(size_t)(qf * 16 + lg * 4 + r) * 512 + k] = sc[qf][kfi][r];
    }

  // ---- PV: out(64q x 64d) ----
  f32x4 accO[4] = {};
#pragma unroll
  for (int half = 0; half < 2; ++half) {
    __syncthreads();
#pragma unroll
    for (int it = 0; it < 8; ++it) {  // stage V half as [64 d][256 k], swizzled source
      const int ci = w * 8 + it;
      const int row = ci * 2 + (lane >> 5);
      const int s = lane & 31;
      GLOAD16(Vg + (size_t)row * 512 + half * 256 + ((s ^ (row & 7)) << 3),
              (char*)Ks + ci * 1024);
    }
#pragma unroll
    for (int qf = 0; qf < 4; ++qf)  // stage P half (bf16) swizzled
#pragma unroll
      for (int r = 0; r < 4; ++r) {
        const int q = qf * 16 + lg * 4 + r;
#pragma unroll
        for (int kf = 0; kf < 4; ++kf) {
          const int k = w * 64 + (kf << 4) + lr;
          Ps[q * 256 + (((k >> 3) ^ (q & 7)) << 3) + (k & 7)] = f2b(sc[qf][half * 4 + kf][r]);
        }
      }
    __syncthreads();
#pragma unroll
    for (int ks = 0; ks < 256; ks += 32) {
      const int sl0 = ks >> 3;
      const int q = w * 16 + lr;
      const bf16x8 af = *(const bf16x8*)&Ps[q * 256 + (((sl0 + lg) ^ (q & 7)) << 3)];
#pragma unroll
      for (int df = 0; df < 4; ++df) {
        const int row = df * 16 + lr;
        const bf16x8 vb = *(const bf16x8*)&Ks[row * 256 + (((sl0 + lg) ^ (row & 7)) << 3)];
        accO[df] = __builtin_amdgcn_mfma_f32_16x16x32_bf16(af, vb, accO[df], 0, 0, 0);
      }
    }
  }

  const int growb = (bid >> 3) * 512 + q0 + w * 16 + lg * 4;
#pragma unroll
  for (int df = 0; df < 4; ++df)
#pragma unroll
    for (int r = 0; r < 4; ++r)
      ao16[(size_t)(growb + r) * 512 + h * 64 + df * 16 + lr] = f2b(accO[df][r]);
}

// ---------------- launcher ----------------
extern "C" void kernel_launch(void* const* d_in, const int* in_sizes, int n_in,
                              void* d_out, int out_size, void* d_ws, size_t ws_size,
                              hipStream_t stream) {
  const float* in_f = (const float*)d_in[1];
  const float* in_fkv = (const float*)d_in[2];
  const float* Wq = (const float*)d_in[3];
  const float* Wk = (const float*)d_in[4];
  const float* Wv = (const float*)d_in[5];
  const float* Wz = (const float*)d_in[6];
  const float* bz = (const float*)d_in[7];
  const float* W1 = (const float*)d_in[8];
  const float* b1 = (const float*)d_in[9];
  const float* W2 = (const float*)d_in[10];
  const float* b2 = (const float*)d_in[11];

  float* out_f = (float*)d_out;
  float* attw = out_f + (size_t)MROWS * DDIM;

  const size_t TSB = (size_t)MROWS * DDIM;
  unsigned short* us = (unsigned short*)d_ws;
  unsigned short* a16 = us;
  unsigned short* akv16 = us + TSB;
  unsigned short* q16 = us + 2 * TSB;
  unsigned short* k16 = us + 3 * TSB;
  unsigned short* h16 = us + 4 * TSB;
  unsigned short* ao16 = us + 5 * TSB;
  unsigned short* vT = us + 6 * TSB;
  unsigned short* w16 = us + 7 * TSB;  // 6 * 262144 ushorts
  float* fbase = (float*)(us + 7 * TSB + 6 * 262144);
  float* part0 = fbase;
  float* part1 = fbase + 1024;
  float* part_q = fbase + 2048;
  float* part_k = fbase + 3072;

  dim3 sg(16, 32);
  gn_stats_partial<<<sg, 256, 0, stream>>>(in_f, part0);
  gn_stats_partial<<<sg, 256, 0, stream>>>(in_fkv, part1);
  cvt_gn<<<2048, 256, 0, stream>>>(in_f, part0, a16);
  cvt_gn<<<2048, 256, 0, stream>>>(in_fkv, part1, akv16);
  cvt_w<<<dim3(128, 6), 256, 0, stream>>>(Wq, Wk, Wv, Wz, W1, W2, w16);

  dim3 gg(128, 4);
  gemm_bf16<0, 1><<<gg, 256, 0, stream>>>(a16, w16 + 0 * 262144, q16, nullptr, part_q);
  gemm_bf16<0, 1><<<gg, 256, 0, stream>>>(akv16, w16 + 1 * 262144, k16, nullptr, part_k);
  gemm_bf16<2, 0><<<gg, 256, 0, stream>>>(akv16, w16 + 2 * 262144, vT, nullptr, nullptr);
  gemm_bf16<1, 0><<<gg, 256, 0, stream>>>(a16, w16 + 4 * 262144, h16, b1, nullptr);

  attn_fused<<<dim3(256, 8), 256, 0, stream>>>(q16, k16, vT, part_q, part_k, attw, ao16);

  gemm_final<<<gg, 256, 0, stream>>>(ao16, h16, w16 + 3 * 262144, w16 + 5 * 262144, out_f, bz,
                                     b2, in_f);
}